// Round 1
// baseline (2102.466 us; speedup 1.0000x reference)
//
#include <hip/hip_runtime.h>
#include <math.h>

// Problem constants
static constexpr int BN = 1024;   // batch
static constexpr int PN = 196;    // patches
static constexpr int HN = 512;    // hidden == att dim
static constexpr int NP1 = 197;   // P+1 (with sentinel)

// ---------------------------------------------------------------------------
// Generic tiled fp32 GEMM: C = act((A [+ A2]) @ W + bias)
//   A: M x 512 row-major, W: 512 x 512 row-major, C: M x 512
//   BM=64, BN=64, BK=16, 256 threads, 4x4 outputs/thread.
//   grid = (N/64, M/64)
// ACT: 0 = none, 1 = relu, 2 = tanh
// ---------------------------------------------------------------------------
template<int ACT, bool HAS_A2>
__global__ __launch_bounds__(256)
void gemm512_kernel(const float* __restrict__ Am, const float* __restrict__ A2,
                    const float* __restrict__ W, const float* __restrict__ bias,
                    float* __restrict__ C)
{
    __shared__ float As[64][20];   // [m][k], row stride 20 floats (80B, 16B aligned)
    __shared__ float Ws[16][64];   // [k][n]

    const int tid = threadIdx.x;
    const int tx = tid & 15;       // col group (4 cols each)
    const int ty = tid >> 4;       // row group (4 rows each)
    const int m0 = blockIdx.y * 64;
    const int n0 = blockIdx.x * 64;
    const int lm  = tid >> 2;            // A-load row 0..63
    const int lk4 = (tid & 3) << 2;      // A-load k offset 0/4/8/12
    const int wk  = tid >> 4;            // W-load k 0..15
    const int wn4 = (tid & 15) << 2;     // W-load n offset

    float c[4][4] = {};

    for (int kt = 0; kt < 512; kt += 16) {
        float4 a = *(const float4*)(Am + (size_t)(m0 + lm) * 512 + kt + lk4);
        if (HAS_A2) {
            float4 a2 = *(const float4*)(A2 + (size_t)(m0 + lm) * 512 + kt + lk4);
            a.x += a2.x; a.y += a2.y; a.z += a2.z; a.w += a2.w;
        }
        float4 w = *(const float4*)(W + (size_t)(kt + wk) * 512 + n0 + wn4);
        __syncthreads();
        *(float4*)&As[lm][lk4] = a;
        *(float4*)&Ws[wk][wn4] = w;
        __syncthreads();
        #pragma unroll
        for (int k = 0; k < 16; ++k) {
            const float a0 = As[ty * 4 + 0][k];
            const float a1 = As[ty * 4 + 1][k];
            const float a2v = As[ty * 4 + 2][k];
            const float a3 = As[ty * 4 + 3][k];
            const float4 wv = *(const float4*)&Ws[k][tx << 2];
            c[0][0] += a0 * wv.x;  c[0][1] += a0 * wv.y;  c[0][2] += a0 * wv.z;  c[0][3] += a0 * wv.w;
            c[1][0] += a1 * wv.x;  c[1][1] += a1 * wv.y;  c[1][2] += a1 * wv.z;  c[1][3] += a1 * wv.w;
            c[2][0] += a2v * wv.x; c[2][1] += a2v * wv.y; c[2][2] += a2v * wv.z; c[2][3] += a2v * wv.w;
            c[3][0] += a3 * wv.x;  c[3][1] += a3 * wv.y;  c[3][2] += a3 * wv.z;  c[3][3] += a3 * wv.w;
        }
    }

    const float4 bv = *(const float4*)(bias + n0 + (tx << 2));
    #pragma unroll
    for (int i = 0; i < 4; ++i) {
        const int row = m0 + ty * 4 + i;
        float4 v = make_float4(c[i][0] + bv.x, c[i][1] + bv.y, c[i][2] + bv.z, c[i][3] + bv.w);
        if (ACT == 1) { v.x = fmaxf(v.x, 0.f); v.y = fmaxf(v.y, 0.f); v.z = fmaxf(v.z, 0.f); v.w = fmaxf(v.w, 0.f); }
        if (ACT == 2) { v.x = tanhf(v.x); v.y = tanhf(v.y); v.z = tanhf(v.z); v.w = tanhf(v.w); }
        *(float4*)(C + (size_t)row * 512 + n0 + (tx << 2)) = v;
    }
}

// ---------------------------------------------------------------------------
// Big fused kernel: alphas[r] += sum_n W_al[n] * tanh( (spatial@W_va)[r,n]
//                                                      + b_va[n] + hatt[b(r),n] )
// Same GEMM tiling; epilogue reduces the 64x64 tile over n and atomically
// accumulates per-row partials. grid = (8 n-tiles, 3136 row-tiles).
// Note: + b_al is skipped — it is constant across p so softmax is invariant.
// ---------------------------------------------------------------------------
__global__ __launch_bounds__(256)
void alpha_gemm_kernel(const float* __restrict__ S, const float* __restrict__ Wva,
                       const float* __restrict__ bva, const float* __restrict__ hatt,
                       const float* __restrict__ Wal, float* __restrict__ alph)
{
    __shared__ float As[64][20];
    __shared__ float Ws[16][64];

    const int tid = threadIdx.x;
    const int tx = tid & 15;
    const int ty = tid >> 4;
    const int m0 = blockIdx.y * 64;
    const int n0 = blockIdx.x * 64;
    const int lm  = tid >> 2;
    const int lk4 = (tid & 3) << 2;
    const int wk  = tid >> 4;
    const int wn4 = (tid & 15) << 2;

    float c[4][4] = {};

    for (int kt = 0; kt < 512; kt += 16) {
        const float4 a = *(const float4*)(S + (size_t)(m0 + lm) * 512 + kt + lk4);
        const float4 w = *(const float4*)(Wva + (size_t)(kt + wk) * 512 + n0 + wn4);
        __syncthreads();
        *(float4*)&As[lm][lk4] = a;
        *(float4*)&Ws[wk][wn4] = w;
        __syncthreads();
        #pragma unroll
        for (int k = 0; k < 16; ++k) {
            const float a0 = As[ty * 4 + 0][k];
            const float a1 = As[ty * 4 + 1][k];
            const float a2v = As[ty * 4 + 2][k];
            const float a3 = As[ty * 4 + 3][k];
            const float4 wv = *(const float4*)&Ws[k][tx << 2];
            c[0][0] += a0 * wv.x;  c[0][1] += a0 * wv.y;  c[0][2] += a0 * wv.z;  c[0][3] += a0 * wv.w;
            c[1][0] += a1 * wv.x;  c[1][1] += a1 * wv.y;  c[1][2] += a1 * wv.z;  c[1][3] += a1 * wv.w;
            c[2][0] += a2v * wv.x; c[2][1] += a2v * wv.y; c[2][2] += a2v * wv.z; c[2][3] += a2v * wv.w;
            c[3][0] += a3 * wv.x;  c[3][1] += a3 * wv.y;  c[3][2] += a3 * wv.z;  c[3][3] += a3 * wv.w;
        }
    }

    // epilogue: tanh + dot with W_al, reduce over this n-tile
    float part[4];
    #pragma unroll
    for (int i = 0; i < 4; ++i) {
        const int row = m0 + ty * 4 + i;
        const int b = row / 196;
        float s = 0.f;
        #pragma unroll
        for (int j = 0; j < 4; ++j) {
            const int n = n0 + (tx << 2) + j;
            const float t = tanhf(c[i][j] + bva[n] + hatt[(size_t)b * 512 + n]);
            s += t * Wal[n];
        }
        part[i] = s;
    }

    __syncthreads();
    float* red = &As[0][0];   // reuse LDS: 64 rows x 16 tx partials
    #pragma unroll
    for (int i = 0; i < 4; ++i) red[(ty * 4 + i) * 16 + tx] = part[i];
    __syncthreads();
    if (tid < 64) {
        float s = 0.f;
        #pragma unroll
        for (int t = 0; t < 16; ++t) s += red[tid * 16 + t];
        atomicAdd(&alph[m0 + tid], s);
    }
}

// ---------------------------------------------------------------------------
// Per-batch: sentinel alpha + softmax over 197 + weighted context sum.
// grid = 1024 blocks, 256 threads. Writes attention_weights, beta, context.
// ---------------------------------------------------------------------------
__global__ __launch_bounds__(256)
void softmax_context_kernel(const float* __restrict__ alph,    // B x 196 raw alphas
                            const float* __restrict__ satt,    // B x 512
                            const float* __restrict__ hatt,    // B x 512
                            const float* __restrict__ Wal,     // 512
                            const float* __restrict__ spatial, // B x 196 x 512
                            const float* __restrict__ sa,      // sentinel_affine B x 512
                            float* __restrict__ wout,          // B x 197 (output region)
                            float* __restrict__ beta,          // B
                            float* __restrict__ context)       // B x 512 (ws)
{
    const int b = blockIdx.x;
    const int tid = threadIdx.x;
    const int lane = tid & 63;
    const int wid = tid >> 6;

    __shared__ float sw[NP1];
    __shared__ float rbuf[8];

    // sentinel alpha = sum_a W_al[a] * tanh(satt[b,a] + hatt[b,a])
    float s = 0.f;
    for (int a = tid; a < 512; a += 256)
        s += tanhf(satt[(size_t)b * 512 + a] + hatt[(size_t)b * 512 + a]) * Wal[a];
    #pragma unroll
    for (int off = 32; off >= 1; off >>= 1) s += __shfl_down(s, off);
    if (lane == 0) rbuf[wid] = s;
    __syncthreads();
    if (tid == 0) sw[196] = rbuf[0] + rbuf[1] + rbuf[2] + rbuf[3];
    if (tid < 196) sw[tid] = alph[(size_t)b * 196 + tid];
    __syncthreads();

    // softmax over 197
    const float v = (tid < NP1) ? sw[tid] : -INFINITY;
    float m = v;
    #pragma unroll
    for (int off = 32; off >= 1; off >>= 1) m = fmaxf(m, __shfl_down(m, off));
    if (lane == 0) rbuf[wid] = m;
    __syncthreads();
    m = fmaxf(fmaxf(rbuf[0], rbuf[1]), fmaxf(rbuf[2], rbuf[3]));
    const float e = (tid < NP1) ? expf(v - m) : 0.f;
    float l = e;
    #pragma unroll
    for (int off = 32; off >= 1; off >>= 1) l += __shfl_down(l, off);
    if (lane == 0) rbuf[4 + wid] = l;
    __syncthreads();
    l = rbuf[4] + rbuf[5] + rbuf[6] + rbuf[7];
    const float w = e / l;
    if (tid < NP1) { wout[(size_t)b * NP1 + tid] = w; sw[tid] = w; }
    if (tid == 196) beta[b] = w;
    __syncthreads();

    // context[b,h] = sum_p w[p]*spatial[b,p,h] + w[196]*sa[b,h]
    const int h = tid * 2;
    float c0 = 0.f, c1 = 0.f;
    #pragma unroll 4
    for (int p = 0; p < 196; ++p) {
        const float wp = sw[p];
        const float2 sv = *(const float2*)(spatial + ((size_t)b * 196 + p) * 512 + h);
        c0 += wp * sv.x; c1 += wp * sv.y;
    }
    {
        const float wp = sw[196];
        const float2 sv = *(const float2*)(sa + (size_t)b * 512 + h);
        c0 += wp * sv.x; c1 += wp * sv.y;
    }
    *(float2*)(context + (size_t)b * 512 + h) = make_float2(c0, c1);
}

// ---------------------------------------------------------------------------
extern "C" void kernel_launch(void* const* d_in, const int* in_sizes, int n_in,
                              void* d_out, int out_size, void* d_ws, size_t ws_size,
                              hipStream_t stream)
{
    const float* spatial = (const float*)d_in[0];
    const float* dec     = (const float*)d_in[1];
    const float* st      = (const float*)d_in[2];
    const float* W_sa    = (const float*)d_in[3];
    const float* b_sa    = (const float*)d_in[4];
    const float* W_satt  = (const float*)d_in[5];
    const float* b_satt  = (const float*)d_in[6];
    const float* W_ha    = (const float*)d_in[7];
    const float* b_ha    = (const float*)d_in[8];
    const float* W_hatt  = (const float*)d_in[9];
    const float* b_hatt  = (const float*)d_in[10];
    const float* W_va    = (const float*)d_in[11];
    const float* b_va    = (const float*)d_in[12];
    const float* W_al    = (const float*)d_in[13];
    // d_in[14] = b_al: constant shift across p -> softmax invariant, unused.
    const float* W_ch    = (const float*)d_in[15];
    const float* b_ch    = (const float*)d_in[16];

    float* out  = (float*)d_out;                 // B x 512
    float* wout = out + (size_t)BN * HN;         // B x 197
    float* beta = wout + (size_t)BN * NP1;       // B

    float* ws   = (float*)d_ws;
    float* sa   = ws;                            // B x 512
    float* ha   = sa + (size_t)BN * HN;          // B x 512
    float* satt = ha + (size_t)BN * HN;          // B x 512
    float* hatt = satt + (size_t)BN * HN;        // B x 512
    float* alph = hatt + (size_t)BN * HN;        // B x 196
    float* ctx  = alph + (size_t)BN * PN;        // B x 512

    const dim3 blk(256);
    const dim3 g_small(8, 16);   // 512/64 n-tiles, 1024/64 m-tiles

    // sentinel_affine = relu(st @ W_sa + b_sa); hidden_affine = tanh(dec @ W_ha + b_ha)
    gemm512_kernel<1, false><<<g_small, blk, 0, stream>>>(st,  nullptr, W_sa, b_sa, sa);
    gemm512_kernel<2, false><<<g_small, blk, 0, stream>>>(dec, nullptr, W_ha, b_ha, ha);
    // sentinel_attention = sa @ W_satt + b_satt; hidden_attention = ha @ W_hatt + b_hatt
    gemm512_kernel<0, false><<<g_small, blk, 0, stream>>>(sa, nullptr, W_satt, b_satt, satt);
    gemm512_kernel<0, false><<<g_small, blk, 0, stream>>>(ha, nullptr, W_hatt, b_hatt, hatt);

    // raw alphas for the 196 spatial positions (fused big GEMM + tanh + dot W_al)
    hipMemsetAsync(alph, 0, (size_t)BN * PN * sizeof(float), stream);
    alpha_gemm_kernel<<<dim3(8, 3136), blk, 0, stream>>>(spatial, W_va, b_va, hatt, W_al, alph);

    // sentinel alpha + softmax + attention weights + beta + context
    softmax_context_kernel<<<dim3(BN), blk, 0, stream>>>(alph, satt, hatt, W_al, spatial,
                                                         sa, wout, beta, ctx);

    // out = tanh((context + hidden_affine) @ W_ch + b_ch)
    gemm512_kernel<2, true><<<g_small, blk, 0, stream>>>(ctx, ha, W_ch, b_ch, out);
}

// Round 5
// 1180.431 us; speedup vs baseline: 1.7811x; 1.7811x over previous
//
#include <hip/hip_runtime.h>
#include <math.h>

static constexpr int BN = 1024;   // batch
static constexpr int PN = 196;    // patches
static constexpr int HN = 512;    // hidden == att dim
static constexpr int NP1 = 197;   // P+1 (with sentinel)

typedef __attribute__((ext_vector_type(8))) short short8;      // 8 x bf16 (4 VGPR)
typedef __attribute__((ext_vector_type(4))) float f32x4;       // MFMA acc
typedef __attribute__((ext_vector_type(4))) unsigned short us4; // 8B bf16 pack

__device__ __forceinline__ unsigned short f2bf(float f) {
    union { float f; unsigned int u; } v; v.f = f;
    unsigned int r = v.u + 0x7FFFu + ((v.u >> 16) & 1u);   // RNE
    return (unsigned short)(r >> 16);
}

// fast tanh for pre-softmax path: 1 - 2/(exp(2x)+1); saturates correctly.
__device__ __forceinline__ float fast_tanh(float x) {
    return 1.f - 2.f / (__expf(2.f * x) + 1.f);
}

// ---------------------------------------------------------------------------
// W_va fp32 [k][n] (512x512) -> Wt bf16 [n][k]  (B-operand friendly layout)
// ---------------------------------------------------------------------------
__global__ __launch_bounds__(256)
void wt_transpose_kernel(const float* __restrict__ W, unsigned short* __restrict__ Wt)
{
    __shared__ float tile[16][17];
    const int tx = threadIdx.x & 15, ty = threadIdx.x >> 4;
    const int k0 = blockIdx.x * 16, n0 = blockIdx.y * 16;
    tile[ty][tx] = W[(k0 + ty) * 512 + n0 + tx];
    __syncthreads();
    Wt[(size_t)(n0 + ty) * 512 + k0 + tx] = f2bf(tile[tx][ty]);
}

// ---------------------------------------------------------------------------
// Fused big kernel (MFMA): for a 64-row strip, all N=512:
//   alphas[r] = sum_n W_al[n] * tanh( (spatial@W_va)[r,n] + b_va[n] + hatt[b(r),n] )
// A (spatial rows, bf16, XOR-swizzled) staged ONCE in 64 KB LDS -> spatial read
// exactly once from HBM. B streamed per-lane from the L2-resident bf16 Wt copy.
// No barriers in the compute loop; no atomics (full N per block).
// 4 waves in a 2x2 grid over the 64x64 C tile; 8 n-chunks of 64.
// ---------------------------------------------------------------------------
__global__ __launch_bounds__(256, 2)
void alpha_mfma_kernel(const float* __restrict__ S, const unsigned short* __restrict__ Wt,
                       const float* __restrict__ bva, const float* __restrict__ hatt,
                       const float* __restrict__ Wal, float* __restrict__ alph)
{
    __shared__ unsigned short Ash[64 * 512];   // 64 KB bf16 A tile (swizzled)
    char* const base = (char*)Ash;

    const int tid = threadIdx.x;
    const int m0 = blockIdx.x * 64;

    // ---- stage A: fp32 global -> bf16 LDS, swizzle byte ^= (row&7)<<4 ----
    #pragma unroll
    for (int i = 0; i < 32; ++i) {
        const int idx = tid + 256 * i;        // 0..8191 float4 slots
        const int row = idx >> 7;             // 0..63
        const int f4  = idx & 127;            // float4 within row
        const float4 v = *(const float4*)(S + (size_t)(m0 + row) * 512 + (f4 << 2));
        us4 u;
        u.x = f2bf(v.x); u.y = f2bf(v.y); u.z = f2bf(v.z); u.w = f2bf(v.w);
        const int byte = row * 1024 + (((f4 << 3)) ^ ((row & 7) << 4));
        *(us4*)(base + byte) = u;
    }
    __syncthreads();

    const int l  = tid & 63;
    const int w  = tid >> 6;
    const int wm = w & 1;          // row half (32)
    const int wn = w >> 1;         // col half (32)
    const int lr = l & 15;
    const int lg = l >> 4;         // 0..3

    // fixed per-lane output rows (C layout: col=lane&15, row=(lane>>4)*4+reg)
    int rowl[8];
    const float* hp[8];
    #pragma unroll
    for (int mi = 0; mi < 2; ++mi)
        #pragma unroll
        for (int r = 0; r < 4; ++r) {
            const int rl = wm * 32 + mi * 16 + lg * 4 + r;
            rowl[mi * 4 + r] = rl;
            hp[mi * 4 + r] = hatt + (size_t)((m0 + rl) / 196) * 512;
        }

    const int swz = (lr & 7) << 4;
    const int arow0 = (wm * 32 + lr) * 1024;        // A byte base, mi=0
    const int arow1 = arow0 + 16 * 1024;            // mi=1

    float apart[8] = {0, 0, 0, 0, 0, 0, 0, 0};

    for (int nc = 0; nc < 8; ++nc) {
        const int n0c = nc * 64;
        const unsigned short* bp0 = Wt + (size_t)(n0c + wn * 32 + lr) * 512 + lg * 8;
        const unsigned short* bp1 = bp0 + 16 * 512;
        f32x4 acc00 = {0,0,0,0}, acc01 = {0,0,0,0}, acc10 = {0,0,0,0}, acc11 = {0,0,0,0};
        #pragma unroll 4
        for (int kt = 0; kt < 16; ++kt) {
            const int koff = ((kt << 6) + (lg << 4)) ^ swz;
            const short8 a0 = *(const short8*)(base + arow0 + koff);
            const short8 a1 = *(const short8*)(base + arow1 + koff);
            const short8 b0 = *(const short8*)(bp0 + (kt << 5));
            const short8 b1 = *(const short8*)(bp1 + (kt << 5));
            acc00 = __builtin_amdgcn_mfma_f32_16x16x32_bf16(a0, b0, acc00, 0, 0, 0);
            acc01 = __builtin_amdgcn_mfma_f32_16x16x32_bf16(a0, b1, acc01, 0, 0, 0);
            acc10 = __builtin_amdgcn_mfma_f32_16x16x32_bf16(a1, b0, acc10, 0, 0, 0);
            acc11 = __builtin_amdgcn_mfma_f32_16x16x32_bf16(a1, b1, acc11, 0, 0, 0);
        }
        // epilogue: tanh + dot(W_al) for this 64-col chunk
        #pragma unroll
        for (int nj = 0; nj < 2; ++nj) {
            const int n = n0c + wn * 32 + nj * 16 + lr;
            const float bv = bva[n], wv = Wal[n];
            const f32x4 c0 = nj ? acc01 : acc00;
            const f32x4 c1 = nj ? acc11 : acc10;
            #pragma unroll
            for (int r = 0; r < 4; ++r) {
                apart[r]     += fast_tanh(c0[r] + bv + hp[r][n])     * wv;
                apart[4 + r] += fast_tanh(c1[r] + bv + hp[4 + r][n]) * wv;
            }
        }
    }

    // reduce over the 16 col-lanes (bits 0..3 of lane id)
    #pragma unroll
    for (int i = 0; i < 8; ++i) {
        float v = apart[i];
        v += __shfl_xor(v, 1); v += __shfl_xor(v, 2);
        v += __shfl_xor(v, 4); v += __shfl_xor(v, 8);
        apart[i] = v;
    }
    __syncthreads();                       // all waves done reading Ash
    float* als = (float*)Ash;              // alias: 128 floats (2 col-halves x 64 rows)
    if (lr == 0) {
        #pragma unroll
        for (int i = 0; i < 8; ++i) als[wn * 64 + rowl[i]] = apart[i];
    }
    __syncthreads();
    if (tid < 64) alph[m0 + tid] = als[tid] + als[64 + tid];
}

// ---------------------------------------------------------------------------
// Generic tiled fp32 GEMM: C = act((A [+ A2]) @ W + bias); small/final GEMMs.
// ---------------------------------------------------------------------------
template<int ACT, bool HAS_A2>
__global__ __launch_bounds__(256)
void gemm512_kernel(const float* __restrict__ Am, const float* __restrict__ A2,
                    const float* __restrict__ W, const float* __restrict__ bias,
                    float* __restrict__ C)
{
    __shared__ float As[64][20];
    __shared__ float Ws[16][64];

    const int tid = threadIdx.x;
    const int tx = tid & 15;
    const int ty = tid >> 4;
    const int m0 = blockIdx.y * 64;
    const int n0 = blockIdx.x * 64;
    const int lm  = tid >> 2;
    const int lk4 = (tid & 3) << 2;
    const int wk  = tid >> 4;
    const int wn4 = (tid & 15) << 2;

    float c[4][4] = {};

    for (int kt = 0; kt < 512; kt += 16) {
        float4 a = *(const float4*)(Am + (size_t)(m0 + lm) * 512 + kt + lk4);
        if (HAS_A2) {
            float4 a2 = *(const float4*)(A2 + (size_t)(m0 + lm) * 512 + kt + lk4);
            a.x += a2.x; a.y += a2.y; a.z += a2.z; a.w += a2.w;
        }
        float4 wv4 = *(const float4*)(W + (size_t)(kt + wk) * 512 + n0 + wn4);
        __syncthreads();
        *(float4*)&As[lm][lk4] = a;
        *(float4*)&Ws[wk][wn4] = wv4;
        __syncthreads();
        #pragma unroll
        for (int k = 0; k < 16; ++k) {
            const float a0 = As[ty * 4 + 0][k];
            const float a1 = As[ty * 4 + 1][k];
            const float a2v = As[ty * 4 + 2][k];
            const float a3 = As[ty * 4 + 3][k];
            const float4 wv = *(const float4*)&Ws[k][tx << 2];
            c[0][0] += a0 * wv.x;  c[0][1] += a0 * wv.y;  c[0][2] += a0 * wv.z;  c[0][3] += a0 * wv.w;
            c[1][0] += a1 * wv.x;  c[1][1] += a1 * wv.y;  c[1][2] += a1 * wv.z;  c[1][3] += a1 * wv.w;
            c[2][0] += a2v * wv.x; c[2][1] += a2v * wv.y; c[2][2] += a2v * wv.z; c[2][3] += a2v * wv.w;
            c[3][0] += a3 * wv.x;  c[3][1] += a3 * wv.y;  c[3][2] += a3 * wv.z;  c[3][3] += a3 * wv.w;
        }
    }

    const float4 bv = *(const float4*)(bias + n0 + (tx << 2));
    #pragma unroll
    for (int i = 0; i < 4; ++i) {
        const int row = m0 + ty * 4 + i;
        float4 v = make_float4(c[i][0] + bv.x, c[i][1] + bv.y, c[i][2] + bv.z, c[i][3] + bv.w);
        if (ACT == 1) { v.x = fmaxf(v.x, 0.f); v.y = fmaxf(v.y, 0.f); v.z = fmaxf(v.z, 0.f); v.w = fmaxf(v.w, 0.f); }
        if (ACT == 2) { v.x = tanhf(v.x); v.y = tanhf(v.y); v.z = tanhf(v.z); v.w = tanhf(v.w); }
        *(float4*)(C + (size_t)row * 512 + n0 + (tx << 2)) = v;
    }
}

// ---------------------------------------------------------------------------
// Per-batch: sentinel alpha + softmax over 197 + weighted context (float4,
// 2-way p-split so all 256 lanes stream 16B each).
// ---------------------------------------------------------------------------
__global__ __launch_bounds__(256)
void softmax_context_kernel(const float* __restrict__ alph, const float* __restrict__ satt,
                            const float* __restrict__ hatt, const float* __restrict__ Wal,
                            const float* __restrict__ spatial, const float* __restrict__ sa,
                            float* __restrict__ wout, float* __restrict__ beta,
                            float* __restrict__ context)
{
    const int b = blockIdx.x;
    const int tid = threadIdx.x;
    const int lane = tid & 63;
    const int wid = tid >> 6;

    __shared__ float sw[NP1];
    __shared__ float rbuf[8];
    __shared__ float cbuf[512];

    // sentinel alpha
    float s = 0.f;
    for (int a = tid; a < 512; a += 256)
        s += tanhf(satt[(size_t)b * 512 + a] + hatt[(size_t)b * 512 + a]) * Wal[a];
    #pragma unroll
    for (int off = 32; off >= 1; off >>= 1) s += __shfl_down(s, off);
    if (lane == 0) rbuf[wid] = s;
    __syncthreads();
    if (tid == 0) sw[196] = rbuf[0] + rbuf[1] + rbuf[2] + rbuf[3];
    if (tid < 196) sw[tid] = alph[(size_t)b * 196 + tid];
    __syncthreads();

    // softmax over 197
    const float v = (tid < NP1) ? sw[tid] : -INFINITY;
    float m = v;
    #pragma unroll
    for (int off = 32; off >= 1; off >>= 1) m = fmaxf(m, __shfl_down(m, off));
    if (lane == 0) rbuf[wid] = m;
    __syncthreads();
    m = fmaxf(fmaxf(rbuf[0], rbuf[1]), fmaxf(rbuf[2], rbuf[3]));
    const float e = (tid < NP1) ? expf(v - m) : 0.f;
    float lsum = e;
    #pragma unroll
    for (int off = 32; off >= 1; off >>= 1) lsum += __shfl_down(lsum, off);
    if (lane == 0) rbuf[4 + wid] = lsum;
    __syncthreads();
    lsum = rbuf[4] + rbuf[5] + rbuf[6] + rbuf[7];
    const float wgt = e / lsum;
    if (tid < NP1) { wout[(size_t)b * NP1 + tid] = wgt; sw[tid] = wgt; }
    if (tid == 196) beta[b] = wgt;
    __syncthreads();

    // context[b,:] = sum_p w[p]*spatial[b,p,:] + w[196]*sa[b,:]
    const int hq = (tid & 127) << 2;
    const int ph = tid >> 7;
    float4 c = make_float4(0.f, 0.f, 0.f, 0.f);
    const float* sp = spatial + (size_t)b * 196 * 512 + hq;
    const int p0 = ph * 98;
    #pragma unroll 2
    for (int p = p0; p < p0 + 98; ++p) {
        const float wp = sw[p];
        const float4 sv = *(const float4*)(sp + (size_t)p * 512);
        c.x += wp * sv.x; c.y += wp * sv.y; c.z += wp * sv.z; c.w += wp * sv.w;
    }
    if (ph) *(float4*)(cbuf + hq) = c;
    __syncthreads();
    if (!ph) {
        const float wp = sw[196];
        const float4 sv = *(const float4*)(sa + (size_t)b * 512 + hq);
        const float4 o = *(const float4*)(cbuf + hq);
        c.x += wp * sv.x + o.x; c.y += wp * sv.y + o.y;
        c.z += wp * sv.z + o.z; c.w += wp * sv.w + o.w;
        *(float4*)(context + (size_t)b * 512 + hq) = c;
    }
}

// ---------------------------------------------------------------------------
extern "C" void kernel_launch(void* const* d_in, const int* in_sizes, int n_in,
                              void* d_out, int out_size, void* d_ws, size_t ws_size,
                              hipStream_t stream)
{
    const float* spatial = (const float*)d_in[0];
    const float* dec     = (const float*)d_in[1];
    const float* st      = (const float*)d_in[2];
    const float* W_sa    = (const float*)d_in[3];
    const float* b_sa    = (const float*)d_in[4];
    const float* W_satt  = (const float*)d_in[5];
    const float* b_satt  = (const float*)d_in[6];
    const float* W_ha    = (const float*)d_in[7];
    const float* b_ha    = (const float*)d_in[8];
    const float* W_hatt  = (const float*)d_in[9];
    const float* b_hatt  = (const float*)d_in[10];
    const float* W_va    = (const float*)d_in[11];
    const float* b_va    = (const float*)d_in[12];
    const float* W_al    = (const float*)d_in[13];
    // d_in[14] = b_al: constant across p -> softmax invariant, unused.
    const float* W_ch    = (const float*)d_in[15];
    const float* b_ch    = (const float*)d_in[16];

    float* out  = (float*)d_out;                 // B x 512
    float* wout = out + (size_t)BN * HN;         // B x 197
    float* beta = wout + (size_t)BN * NP1;       // B

    float* ws   = (float*)d_ws;
    float* sa   = ws;                            // B x 512
    float* ha   = sa + (size_t)BN * HN;          // B x 512
    float* satt = ha + (size_t)BN * HN;          // B x 512
    float* hatt = satt + (size_t)BN * HN;        // B x 512
    float* alph = hatt + (size_t)BN * HN;        // B x 196
    float* ctx  = alph + (size_t)BN * PN;        // B x 512
    // Wt (bf16 512x512 = 512 KB) aliases the ctx region: Wt is dead before
    // softmax_context writes ctx (stream-ordered).
    unsigned short* Wt = (unsigned short*)ctx;

    const dim3 blk(256);
    const dim3 g_small(8, 16);

    wt_transpose_kernel<<<dim3(32, 32), blk, 0, stream>>>(W_va, Wt);

    gemm512_kernel<1, false><<<g_small, blk, 0, stream>>>(st,  nullptr, W_sa, b_sa, sa);
    gemm512_kernel<2, false><<<g_small, blk, 0, stream>>>(dec, nullptr, W_ha, b_ha, ha);
    gemm512_kernel<0, false><<<g_small, blk, 0, stream>>>(sa, nullptr, W_satt, b_satt, satt);
    gemm512_kernel<0, false><<<g_small, blk, 0, stream>>>(ha, nullptr, W_hatt, b_hatt, hatt);

    alpha_mfma_kernel<<<dim3(3136), blk, 0, stream>>>(spatial, Wt, b_va, hatt, W_al, alph);

    softmax_context_kernel<<<dim3(BN), blk, 0, stream>>>(alph, satt, hatt, W_al, spatial,
                                                         sa, wout, beta, ctx);

    gemm512_kernel<2, true><<<g_small, blk, 0, stream>>>(ctx, ha, W_ch, b_ch, out);
}

// Round 10
// 1073.802 us; speedup vs baseline: 1.9580x; 1.0993x over previous
//
#include <hip/hip_runtime.h>
#include <math.h>

static constexpr int BN = 1024;   // batch
static constexpr int PN = 196;    // patches
static constexpr int HN = 512;    // hidden == att dim
static constexpr int NP1 = 197;   // P+1 (with sentinel)

typedef __attribute__((ext_vector_type(8))) short short8;       // 8 x bf16
typedef __attribute__((ext_vector_type(4))) float f32x4;        // MFMA acc
typedef __attribute__((ext_vector_type(4))) unsigned short us4; // 8B bf16 pack

__device__ __forceinline__ unsigned short f2bf(float f) {
    union { float f; unsigned int u; } v; v.f = f;
    unsigned int r = v.u + 0x7FFFu + ((v.u >> 16) & 1u);   // RNE
    return (unsigned short)(r >> 16);
}

// fast tanh for the pre-softmax path: 1 - 2*rcp(exp(2x)+1); saturates to +-1.
__device__ __forceinline__ float fast_tanh(float x) {
    const float e = __expf(2.f * x);
    return 1.f - 2.f * __builtin_amdgcn_rcpf(e + 1.f);
}

// ---------------------------------------------------------------------------
// W_va fp32 [k][n] (512x512) -> Wt bf16 [n][k]
// ---------------------------------------------------------------------------
__global__ __launch_bounds__(256)
void wt_transpose_kernel(const float* __restrict__ W, unsigned short* __restrict__ Wt)
{
    __shared__ float tile[16][17];
    const int tx = threadIdx.x & 15, ty = threadIdx.x >> 4;
    const int k0 = blockIdx.x * 16, n0 = blockIdx.y * 16;
    tile[ty][tx] = W[(k0 + ty) * 512 + n0 + tx];
    __syncthreads();
    Wt[(size_t)(n0 + ty) * 512 + k0 + tx] = f2bf(tile[tx][ty]);
}

// ---------------------------------------------------------------------------
// alpha kernel v2: block = 32-row strip, all N=512.
//   alphas[r] = sum_n W_al[n] * tanh((spatial@W_va)[r,n] + b_va[n] + hatt[b,n])
// 4 waves; wave w owns ALL 32 rows x 128-col slice (cols w*128..w*128+127):
//   - Wt read exactly once per block (no inter-wave duplication)
//   - 16 MFMAs of reuse per B-load cluster (acc 2x8 f32x4 = 64 VGPR)
//   - A re-read from LDS only 2x per kt (register ct-reuse)
// A staged once: fp32 HBM -> bf16 LDS (32KB), XOR-swizzle byte^=(row&7)<<4.
// ---------------------------------------------------------------------------
__global__ __launch_bounds__(256, 3)
void alpha_mfma2_kernel(const float* __restrict__ S, const unsigned short* __restrict__ Wt,
                        const float* __restrict__ bva, const float* __restrict__ hatt,
                        const float* __restrict__ Wal, float* __restrict__ alph)
{
    __shared__ unsigned short Ash[32 * 512];   // 32 KB bf16 A tile (swizzled)
    char* const base = (char*)Ash;

    const int tid = threadIdx.x;
    const int m0 = blockIdx.x * 32;

    // stage A: 32 rows x 512 cols, fp32 -> bf16, swizzled
    #pragma unroll
    for (int i = 0; i < 16; ++i) {
        const int idx = tid + 256 * i;        // 0..4095 float4 slots
        const int row = idx >> 7;             // 0..31
        const int f4  = idx & 127;
        const float4 v = *(const float4*)(S + (size_t)(m0 + row) * 512 + (f4 << 2));
        us4 u;
        u.x = f2bf(v.x); u.y = f2bf(v.y); u.z = f2bf(v.z); u.w = f2bf(v.w);
        *(us4*)(base + row * 1024 + (((f4 << 3)) ^ ((row & 7) << 4))) = u;
    }
    __syncthreads();

    const int l  = tid & 63;
    const int w  = tid >> 6;       // wave id 0..3 -> col slice
    const int lr = l & 15;
    const int lg = l >> 4;         // 0..3
    const int cb = w << 7;         // col base (128-wide slice)

    const int swz   = (lr & 7) << 4;
    const int arow0 = lr * 1024;          // rows 0..15 (rt=0)
    const int arow1 = (16 + lr) * 1024;   // rows 16..31 (rt=1)

    // B base: lane holds col = cb + ct*16 + lr, k = kt*32 + lg*8 + j
    const unsigned short* bbase = Wt + (size_t)(cb + lr) * 512 + lg * 8;

    f32x4 acc[2][8];
    #pragma unroll
    for (int rt = 0; rt < 2; ++rt)
        #pragma unroll
        for (int ct = 0; ct < 8; ++ct) acc[rt][ct] = (f32x4){0.f, 0.f, 0.f, 0.f};

    #pragma unroll 2
    for (int kt = 0; kt < 16; ++kt) {
        const int koff = ((kt << 6) + (lg << 4)) ^ swz;
        const short8 a0 = *(const short8*)(base + arow0 + koff);
        const short8 a1 = *(const short8*)(base + arow1 + koff);
        const int kk = kt << 5;   // shorts
        #pragma unroll
        for (int ct = 0; ct < 8; ++ct) {
            const short8 b = *(const short8*)(bbase + ct * (16 * 512) + kk);
            acc[0][ct] = __builtin_amdgcn_mfma_f32_16x16x32_bf16(a0, b, acc[0][ct], 0, 0, 0);
            acc[1][ct] = __builtin_amdgcn_mfma_f32_16x16x32_bf16(a1, b, acc[1][ct], 0, 0, 0);
        }
    }

    // epilogue: tanh + dot(W_al); C layout col=lr, row(local)=rt*16+lg*4+r
    const int  bb0  = m0 / 196;
    const bool unib = (bb0 == (m0 + 31) / 196);   // strip within one batch (84%)
    float rowp[8] = {0.f, 0.f, 0.f, 0.f, 0.f, 0.f, 0.f, 0.f};

    #pragma unroll
    for (int ct = 0; ct < 8; ++ct) {
        const int n = cb + ct * 16 + lr;
        const float waln = Wal[n];
        const float bvan = bva[n];
        if (unib) {
            const float h = hatt[(size_t)bb0 * 512 + n] + bvan;
            #pragma unroll
            for (int rt = 0; rt < 2; ++rt)
                #pragma unroll
                for (int r = 0; r < 4; ++r)
                    rowp[rt * 4 + r] += fast_tanh(acc[rt][ct][r] + h) * waln;
        } else {
            #pragma unroll
            for (int rt = 0; rt < 2; ++rt)
                #pragma unroll
                for (int r = 0; r < 4; ++r) {
                    const int grow = m0 + rt * 16 + lg * 4 + r;
                    const float h = hatt[(size_t)(grow / 196) * 512 + n] + bvan;
                    rowp[rt * 4 + r] += fast_tanh(acc[rt][ct][r] + h) * waln;
                }
        }
    }

    // reduce over the 16 col-lanes (lane bits 0..3)
    #pragma unroll
    for (int i = 0; i < 8; ++i) {
        float v = rowp[i];
        v += __shfl_xor(v, 1); v += __shfl_xor(v, 2);
        v += __shfl_xor(v, 4); v += __shfl_xor(v, 8);
        rowp[i] = v;
    }
    __syncthreads();                     // all waves done reading Ash
    float* als = (float*)Ash;            // 4 waves x 32 rows
    if (lr == 0) {
        #pragma unroll
        for (int rt = 0; rt < 2; ++rt)
            #pragma unroll
            for (int r = 0; r < 4; ++r)
                als[w * 32 + rt * 16 + lg * 4 + r] = rowp[rt * 4 + r];
    }
    __syncthreads();
    if (tid < 32)
        alph[m0 + tid] = als[tid] + als[32 + tid] + als[64 + tid] + als[96 + tid];
}

// ---------------------------------------------------------------------------
// fp32 GEMM body, 32x64 tile, 256 threads, 2x4 out/thread. ACT: 0 none/1 relu/2 tanh
// ---------------------------------------------------------------------------
template<int ACT, bool HAS_A2>
__device__ __forceinline__
void gemm32_body(const float* __restrict__ Am, const float* __restrict__ A2,
                 const float* __restrict__ W, const float* __restrict__ bias,
                 float* __restrict__ C, int m0, int n0)
{
    __shared__ float As[32][20];
    __shared__ float Ws[16][64];

    const int tid = threadIdx.x;
    const int tx = tid & 15;
    const int ty = tid >> 4;
    const int lm  = tid >> 2;            // A-load row (tid<128)
    const int lk4 = (tid & 3) << 2;
    const int wk  = tid >> 4;
    const int wn4 = (tid & 15) << 2;

    float c[2][4] = {};

    for (int kt = 0; kt < 512; kt += 16) {
        float4 a = make_float4(0.f, 0.f, 0.f, 0.f);
        if (tid < 128) {
            a = *(const float4*)(Am + (size_t)(m0 + lm) * 512 + kt + lk4);
            if (HAS_A2) {
                const float4 a2 = *(const float4*)(A2 + (size_t)(m0 + lm) * 512 + kt + lk4);
                a.x += a2.x; a.y += a2.y; a.z += a2.z; a.w += a2.w;
            }
        }
        const float4 wv4 = *(const float4*)(W + (size_t)(kt + wk) * 512 + n0 + wn4);
        __syncthreads();
        if (tid < 128) *(float4*)&As[lm][lk4] = a;
        *(float4*)&Ws[wk][wn4] = wv4;
        __syncthreads();
        #pragma unroll
        for (int k = 0; k < 16; ++k) {
            const float a0 = As[ty * 2 + 0][k];
            const float a1 = As[ty * 2 + 1][k];
            const float4 wv = *(const float4*)&Ws[k][tx << 2];
            c[0][0] += a0 * wv.x; c[0][1] += a0 * wv.y; c[0][2] += a0 * wv.z; c[0][3] += a0 * wv.w;
            c[1][0] += a1 * wv.x; c[1][1] += a1 * wv.y; c[1][2] += a1 * wv.z; c[1][3] += a1 * wv.w;
        }
    }

    const float4 bv = *(const float4*)(bias + n0 + (tx << 2));
    #pragma unroll
    for (int i = 0; i < 2; ++i) {
        const int row = m0 + ty * 2 + i;
        float4 v = make_float4(c[i][0] + bv.x, c[i][1] + bv.y, c[i][2] + bv.z, c[i][3] + bv.w);
        if (ACT == 1) { v.x = fmaxf(v.x, 0.f); v.y = fmaxf(v.y, 0.f); v.z = fmaxf(v.z, 0.f); v.w = fmaxf(v.w, 0.f); }
        if (ACT == 2) { v.x = tanhf(v.x); v.y = tanhf(v.y); v.z = tanhf(v.z); v.w = tanhf(v.w); }
        *(float4*)(C + (size_t)row * 512 + n0 + (tx << 2)) = v;
    }
}

// two independent 1024x512x512 GEMMs in one full-GPU launch; grid (8, 64)
template<int ACTX, int ACTY>
__global__ __launch_bounds__(256)
void gemm32_pair_kernel(const float* __restrict__ Ax, const float* __restrict__ Wx,
                        const float* __restrict__ bx, float* __restrict__ Cx,
                        const float* __restrict__ Ay, const float* __restrict__ Wy,
                        const float* __restrict__ by, float* __restrict__ Cy)
{
    const int n0 = blockIdx.x * 64;
    if (blockIdx.y < 32)
        gemm32_body<ACTX, false>(Ax, nullptr, Wx, bx, Cx, blockIdx.y * 32, n0);
    else
        gemm32_body<ACTY, false>(Ay, nullptr, Wy, by, Cy, (blockIdx.y - 32) * 32, n0);
}

// final GEMM: out = tanh((ctx + ha) @ W_ch + b_ch); grid (8, 32)
__global__ __launch_bounds__(256)
void gemm32_fin_kernel(const float* __restrict__ Am, const float* __restrict__ A2,
                       const float* __restrict__ W, const float* __restrict__ bias,
                       float* __restrict__ C)
{
    gemm32_body<2, true>(Am, A2, W, bias, C, blockIdx.y * 32, blockIdx.x * 64);
}

// ---------------------------------------------------------------------------
// Per-batch: sentinel alpha + softmax over 197 + weighted context sum.
// ---------------------------------------------------------------------------
__global__ __launch_bounds__(256)
void softmax_context_kernel(const float* __restrict__ alph, const float* __restrict__ satt,
                            const float* __restrict__ hatt, const float* __restrict__ Wal,
                            const float* __restrict__ spatial, const float* __restrict__ sa,
                            float* __restrict__ wout, float* __restrict__ beta,
                            float* __restrict__ context)
{
    const int b = blockIdx.x;
    const int tid = threadIdx.x;
    const int lane = tid & 63;
    const int wid = tid >> 6;

    __shared__ float sw[NP1];
    __shared__ float rbuf[8];
    __shared__ float cbuf[512];

    // sentinel alpha
    float s = 0.f;
    for (int a = tid; a < 512; a += 256)
        s += tanhf(satt[(size_t)b * 512 + a] + hatt[(size_t)b * 512 + a]) * Wal[a];
    #pragma unroll
    for (int off = 32; off >= 1; off >>= 1) s += __shfl_down(s, off);
    if (lane == 0) rbuf[wid] = s;
    __syncthreads();
    if (tid == 0) sw[196] = rbuf[0] + rbuf[1] + rbuf[2] + rbuf[3];
    if (tid < 196) sw[tid] = alph[(size_t)b * 196 + tid];
    __syncthreads();

    // softmax over 197
    const float v = (tid < NP1) ? sw[tid] : -INFINITY;
    float m = v;
    #pragma unroll
    for (int off = 32; off >= 1; off >>= 1) m = fmaxf(m, __shfl_down(m, off));
    if (lane == 0) rbuf[wid] = m;
    __syncthreads();
    m = fmaxf(fmaxf(rbuf[0], rbuf[1]), fmaxf(rbuf[2], rbuf[3]));
    const float e = (tid < NP1) ? expf(v - m) : 0.f;
    float lsum = e;
    #pragma unroll
    for (int off = 32; off >= 1; off >>= 1) lsum += __shfl_down(lsum, off);
    if (lane == 0) rbuf[4 + wid] = lsum;
    __syncthreads();
    lsum = rbuf[4] + rbuf[5] + rbuf[6] + rbuf[7];
    const float wgt = e / lsum;
    if (tid < NP1) { wout[(size_t)b * NP1 + tid] = wgt; sw[tid] = wgt; }
    if (tid == 196) beta[b] = wgt;
    __syncthreads();

    // context[b,:] = sum_p w[p]*spatial[b,p,:] + w[196]*sa[b,:]
    const int hq = (tid & 127) << 2;
    const int ph = tid >> 7;
    float4 c = make_float4(0.f, 0.f, 0.f, 0.f);
    const float* sp = spatial + (size_t)b * 196 * 512 + hq;
    const int p0 = ph * 98;
    #pragma unroll 2
    for (int p = p0; p < p0 + 98; ++p) {
        const float wp = sw[p];
        const float4 sv = *(const float4*)(sp + (size_t)p * 512);
        c.x += wp * sv.x; c.y += wp * sv.y; c.z += wp * sv.z; c.w += wp * sv.w;
    }
    if (ph) *(float4*)(cbuf + hq) = c;
    __syncthreads();
    if (!ph) {
        const float wp = sw[196];
        const float4 sv = *(const float4*)(sa + (size_t)b * 512 + hq);
        const float4 o = *(const float4*)(cbuf + hq);
        c.x += wp * sv.x + o.x; c.y += wp * sv.y + o.y;
        c.z += wp * sv.z + o.z; c.w += wp * sv.w + o.w;
        *(float4*)(context + (size_t)b * 512 + hq) = c;
    }
}

// ---------------------------------------------------------------------------
extern "C" void kernel_launch(void* const* d_in, const int* in_sizes, int n_in,
                              void* d_out, int out_size, void* d_ws, size_t ws_size,
                              hipStream_t stream)
{
    const float* spatial = (const float*)d_in[0];
    const float* dec     = (const float*)d_in[1];
    const float* st      = (const float*)d_in[2];
    const float* W_sa    = (const float*)d_in[3];
    const float* b_sa    = (const float*)d_in[4];
    const float* W_satt  = (const float*)d_in[5];
    const float* b_satt  = (const float*)d_in[6];
    const float* W_ha    = (const float*)d_in[7];
    const float* b_ha    = (const float*)d_in[8];
    const float* W_hatt  = (const float*)d_in[9];
    const float* b_hatt  = (const float*)d_in[10];
    const float* W_va    = (const float*)d_in[11];
    const float* b_va    = (const float*)d_in[12];
    const float* W_al    = (const float*)d_in[13];
    // d_in[14] = b_al: constant across p -> softmax invariant, unused.
    const float* W_ch    = (const float*)d_in[15];
    const float* b_ch    = (const float*)d_in[16];

    float* out  = (float*)d_out;                 // B x 512
    float* wout = out + (size_t)BN * HN;         // B x 197
    float* beta = wout + (size_t)BN * NP1;       // B

    float* ws   = (float*)d_ws;
    float* sa   = ws;                            // B x 512
    float* ha   = sa + (size_t)BN * HN;          // B x 512
    float* satt = ha + (size_t)BN * HN;          // B x 512
    float* hatt = satt + (size_t)BN * HN;        // B x 512
    float* alph = hatt + (size_t)BN * HN;        // B x 196
    float* ctx  = alph + (size_t)BN * PN;        // B x 512
    // Wt (bf16 512x512 = 512 KB) aliases ctx: dead before ctx is written.
    unsigned short* Wt = (unsigned short*)ctx;

    const dim3 blk(256);

    wt_transpose_kernel<<<dim3(32, 32), blk, 0, stream>>>(W_va, Wt);

    // relu(st@W_sa+b_sa) -> sa  ||  tanh(dec@W_ha+b_ha) -> ha
    gemm32_pair_kernel<1, 2><<<dim3(8, 64), blk, 0, stream>>>(
        st, W_sa, b_sa, sa, dec, W_ha, b_ha, ha);
    // sa@W_satt+b_satt -> satt  ||  ha@W_hatt+b_hatt -> hatt
    gemm32_pair_kernel<0, 0><<<dim3(8, 64), blk, 0, stream>>>(
        sa, W_satt, b_satt, satt, ha, W_hatt, b_hatt, hatt);

    alpha_mfma2_kernel<<<dim3(6272), blk, 0, stream>>>(spatial, Wt, b_va, hatt, W_al, alph);

    softmax_context_kernel<<<dim3(BN), blk, 0, stream>>>(alph, satt, hatt, W_al, spatial,
                                                         sa, wout, beta, ctx);

    gemm32_fin_kernel<<<dim3(8, 32), blk, 0, stream>>>(ctx, ha, W_ch, b_ch, out);
}

// Round 11
// 837.762 us; speedup vs baseline: 2.5096x; 1.2818x over previous
//
#include <hip/hip_runtime.h>
#include <math.h>

static constexpr int BN = 1024;   // batch
static constexpr int PN = 196;    // patches
static constexpr int HN = 512;    // hidden == att dim
static constexpr int NP1 = 197;   // P+1 (with sentinel)

typedef __attribute__((ext_vector_type(8))) short short8;       // 8 x bf16
typedef __attribute__((ext_vector_type(4))) float f32x4;        // MFMA acc
typedef __attribute__((ext_vector_type(4))) unsigned short us4; // 8B bf16 pack

__device__ __forceinline__ unsigned short f2bf(float f) {
    union { float f; unsigned int u; } v; v.f = f;
    unsigned int r = v.u + 0x7FFFu + ((v.u >> 16) & 1u);   // RNE
    return (unsigned short)(r >> 16);
}

// fast tanh for the pre-softmax path: 1 - 2*rcp(exp(2x)+1); saturates to +-1.
__device__ __forceinline__ float fast_tanh(float x) {
    const float e = __expf(2.f * x);
    return 1.f - 2.f * __builtin_amdgcn_rcpf(e + 1.f);
}

// ---------------------------------------------------------------------------
// W_va fp32 [k][n] (512x512) -> Bpack bf16 in MFMA-B-fragment order:
//   frag = nt*16 + kt   (nt: 16-col tile 0..31, kt: 32-k tile 0..15)
//   Bpack[frag*512 + lane*8 + j] = W[kt*32 + (lane>>4)*8 + j][nt*16 + (lane&15)]
// so the alpha kernel's B-load is lane l <- base + l*16B (fully coalesced 1KB).
// Fragment contents per lane identical to the HW-validated Wt[n][k] mapping.
// ---------------------------------------------------------------------------
__global__ __launch_bounds__(256)
void wpack_kernel(const float* __restrict__ W, unsigned short* __restrict__ Bp)
{
    const int nt = blockIdx.x;            // 0..31
    const int kt = blockIdx.y;            // 0..15
    const int lane = threadIdx.x >> 2;    // 0..63
    const int jj   = threadIdx.x & 3;     // 0..3 -> j = 2*jj, 2*jj+1
    const int n = nt * 16 + (lane & 15);
    const int kbase = kt * 32 + (lane >> 4) * 8 + jj * 2;
    const unsigned int v0 = f2bf(W[(size_t)kbase * 512 + n]);
    const unsigned int v1 = f2bf(W[(size_t)(kbase + 1) * 512 + n]);
    unsigned int* dst = (unsigned int*)(Bp + (size_t)(nt * 16 + kt) * 512);
    dst[lane * 4 + jj] = v0 | (v1 << 16);   // coalesced 1KB block write
}

// ---------------------------------------------------------------------------
// alpha kernel v3: identical tiling to v2 (32-row strip, 4 waves, wave owns
// 32 rows x 128 cols) but B comes from Bpack -> every B-load is a contiguous
// 1KB wave-load instead of 16 scattered cache lines (v2's TA bottleneck).
// ---------------------------------------------------------------------------
__global__ __launch_bounds__(256, 3)
void alpha_mfma3_kernel(const float* __restrict__ S, const unsigned short* __restrict__ Bp,
                        const float* __restrict__ bva, const float* __restrict__ hatt,
                        const float* __restrict__ Wal, float* __restrict__ alph)
{
    __shared__ unsigned short Ash[32 * 512];   // 32 KB bf16 A tile (swizzled)
    char* const base = (char*)Ash;

    const int tid = threadIdx.x;
    const int m0 = blockIdx.x * 32;

    // stage A: 32 rows x 512 cols, fp32 -> bf16, swizzled
    #pragma unroll
    for (int i = 0; i < 16; ++i) {
        const int idx = tid + 256 * i;        // 0..4095 float4 slots
        const int row = idx >> 7;             // 0..31
        const int f4  = idx & 127;
        const float4 v = *(const float4*)(S + (size_t)(m0 + row) * 512 + (f4 << 2));
        us4 u;
        u.x = f2bf(v.x); u.y = f2bf(v.y); u.z = f2bf(v.z); u.w = f2bf(v.w);
        *(us4*)(base + row * 1024 + (((f4 << 3)) ^ ((row & 7) << 4))) = u;
    }
    __syncthreads();

    const int l  = tid & 63;
    const int w  = tid >> 6;       // wave id 0..3 -> col slice
    const int lr = l & 15;
    const int lg = l >> 4;         // 0..3
    const int cb = w << 7;         // col base (128-wide slice)

    const int swz   = (lr & 7) << 4;
    const int arow0 = lr * 1024;          // rows 0..15 (rt=0)
    const int arow1 = (16 + lr) * 1024;   // rows 16..31 (rt=1)

    // per-wave packed-B base: frags (w*8+ct)*16 + kt, lane slot l*8 shorts
    const unsigned short* bb = Bp + (size_t)(w * 8 * 16) * 512 + (size_t)l * 8;

    f32x4 acc[2][8];
    #pragma unroll
    for (int rt = 0; rt < 2; ++rt)
        #pragma unroll
        for (int ct = 0; ct < 8; ++ct) acc[rt][ct] = (f32x4){0.f, 0.f, 0.f, 0.f};

    #pragma unroll 2
    for (int kt = 0; kt < 16; ++kt) {
        const int koff = ((kt << 6) + (lg << 4)) ^ swz;
        const short8 a0 = *(const short8*)(base + arow0 + koff);
        const short8 a1 = *(const short8*)(base + arow1 + koff);
        #pragma unroll
        for (int ct = 0; ct < 8; ++ct) {
            const short8 b = *(const short8*)(bb + (((ct << 4) + kt) << 9));
            acc[0][ct] = __builtin_amdgcn_mfma_f32_16x16x32_bf16(a0, b, acc[0][ct], 0, 0, 0);
            acc[1][ct] = __builtin_amdgcn_mfma_f32_16x16x32_bf16(a1, b, acc[1][ct], 0, 0, 0);
        }
    }

    // epilogue: tanh + dot(W_al); C layout col=lr, row(local)=rt*16+lg*4+r
    const int  bb0  = m0 / 196;
    const bool unib = (bb0 == (m0 + 31) / 196);   // strip within one batch (84%)
    float rowp[8] = {0.f, 0.f, 0.f, 0.f, 0.f, 0.f, 0.f, 0.f};

    #pragma unroll
    for (int ct = 0; ct < 8; ++ct) {
        const int n = cb + ct * 16 + lr;
        const float waln = Wal[n];
        const float bvan = bva[n];
        if (unib) {
            const float h = hatt[(size_t)bb0 * 512 + n] + bvan;
            #pragma unroll
            for (int rt = 0; rt < 2; ++rt)
                #pragma unroll
                for (int r = 0; r < 4; ++r)
                    rowp[rt * 4 + r] += fast_tanh(acc[rt][ct][r] + h) * waln;
        } else {
            #pragma unroll
            for (int rt = 0; rt < 2; ++rt)
                #pragma unroll
                for (int r = 0; r < 4; ++r) {
                    const int grow = m0 + rt * 16 + lg * 4 + r;
                    const float h = hatt[(size_t)(grow / 196) * 512 + n] + bvan;
                    rowp[rt * 4 + r] += fast_tanh(acc[rt][ct][r] + h) * waln;
                }
        }
    }

    // reduce over the 16 col-lanes (lane bits 0..3)
    #pragma unroll
    for (int i = 0; i < 8; ++i) {
        float v = rowp[i];
        v += __shfl_xor(v, 1); v += __shfl_xor(v, 2);
        v += __shfl_xor(v, 4); v += __shfl_xor(v, 8);
        rowp[i] = v;
    }
    __syncthreads();                     // all waves done reading Ash
    float* als = (float*)Ash;            // 4 waves x 32 rows
    if (lr == 0) {
        #pragma unroll
        for (int rt = 0; rt < 2; ++rt)
            #pragma unroll
            for (int r = 0; r < 4; ++r)
                als[w * 32 + rt * 16 + lg * 4 + r] = rowp[rt * 4 + r];
    }
    __syncthreads();
    if (tid < 32)
        alph[m0 + tid] = als[tid] + als[32 + tid] + als[64 + tid] + als[96 + tid];
}

// ---------------------------------------------------------------------------
// fp32 GEMM body, 32x64 tile, 256 threads, 2x4 out/thread. ACT: 0 none/1 relu/2 tanh
// ---------------------------------------------------------------------------
template<int ACT, bool HAS_A2>
__device__ __forceinline__
void gemm32_body(const float* __restrict__ Am, const float* __restrict__ A2,
                 const float* __restrict__ W, const float* __restrict__ bias,
                 float* __restrict__ C, int m0, int n0)
{
    __shared__ float As[32][20];
    __shared__ float Ws[16][64];

    const int tid = threadIdx.x;
    const int tx = tid & 15;
    const int ty = tid >> 4;
    const int lm  = tid >> 2;            // A-load row (tid<128)
    const int lk4 = (tid & 3) << 2;
    const int wk  = tid >> 4;
    const int wn4 = (tid & 15) << 2;

    float c[2][4] = {};

    for (int kt = 0; kt < 512; kt += 16) {
        float4 a = make_float4(0.f, 0.f, 0.f, 0.f);
        if (tid < 128) {
            a = *(const float4*)(Am + (size_t)(m0 + lm) * 512 + kt + lk4);
            if (HAS_A2) {
                const float4 a2 = *(const float4*)(A2 + (size_t)(m0 + lm) * 512 + kt + lk4);
                a.x += a2.x; a.y += a2.y; a.z += a2.z; a.w += a2.w;
            }
        }
        const float4 wv4 = *(const float4*)(W + (size_t)(kt + wk) * 512 + n0 + wn4);
        __syncthreads();
        if (tid < 128) *(float4*)&As[lm][lk4] = a;
        *(float4*)&Ws[wk][wn4] = wv4;
        __syncthreads();
        #pragma unroll
        for (int k = 0; k < 16; ++k) {
            const float a0 = As[ty * 2 + 0][k];
            const float a1 = As[ty * 2 + 1][k];
            const float4 wv = *(const float4*)&Ws[k][tx << 2];
            c[0][0] += a0 * wv.x; c[0][1] += a0 * wv.y; c[0][2] += a0 * wv.z; c[0][3] += a0 * wv.w;
            c[1][0] += a1 * wv.x; c[1][1] += a1 * wv.y; c[1][2] += a1 * wv.z; c[1][3] += a1 * wv.w;
        }
    }

    const float4 bv = *(const float4*)(bias + n0 + (tx << 2));
    #pragma unroll
    for (int i = 0; i < 2; ++i) {
        const int row = m0 + ty * 2 + i;
        float4 v = make_float4(c[i][0] + bv.x, c[i][1] + bv.y, c[i][2] + bv.z, c[i][3] + bv.w);
        if (ACT == 1) { v.x = fmaxf(v.x, 0.f); v.y = fmaxf(v.y, 0.f); v.z = fmaxf(v.z, 0.f); v.w = fmaxf(v.w, 0.f); }
        if (ACT == 2) { v.x = tanhf(v.x); v.y = tanhf(v.y); v.z = tanhf(v.z); v.w = tanhf(v.w); }
        *(float4*)(C + (size_t)row * 512 + n0 + (tx << 2)) = v;
    }
}

// two independent 1024x512x512 GEMMs in one full-GPU launch; grid (8, 64)
template<int ACTX, int ACTY>
__global__ __launch_bounds__(256)
void gemm32_pair_kernel(const float* __restrict__ Ax, const float* __restrict__ Wx,
                        const float* __restrict__ bx, float* __restrict__ Cx,
                        const float* __restrict__ Ay, const float* __restrict__ Wy,
                        const float* __restrict__ by, float* __restrict__ Cy)
{
    const int n0 = blockIdx.x * 64;
    if (blockIdx.y < 32)
        gemm32_body<ACTX, false>(Ax, nullptr, Wx, bx, Cx, blockIdx.y * 32, n0);
    else
        gemm32_body<ACTY, false>(Ay, nullptr, Wy, by, Cy, (blockIdx.y - 32) * 32, n0);
}

// final GEMM: out = tanh((ctx + ha) @ W_ch + b_ch); grid (8, 32)
__global__ __launch_bounds__(256)
void gemm32_fin_kernel(const float* __restrict__ Am, const float* __restrict__ A2,
                       const float* __restrict__ W, const float* __restrict__ bias,
                       float* __restrict__ C)
{
    gemm32_body<2, true>(Am, A2, W, bias, C, blockIdx.y * 32, blockIdx.x * 64);
}

// ---------------------------------------------------------------------------
// Per-batch: sentinel alpha + softmax over 197 + weighted context sum.
// ---------------------------------------------------------------------------
__global__ __launch_bounds__(256)
void softmax_context_kernel(const float* __restrict__ alph, const float* __restrict__ satt,
                            const float* __restrict__ hatt, const float* __restrict__ Wal,
                            const float* __restrict__ spatial, const float* __restrict__ sa,
                            float* __restrict__ wout, float* __restrict__ beta,
                            float* __restrict__ context)
{
    const int b = blockIdx.x;
    const int tid = threadIdx.x;
    const int lane = tid & 63;
    const int wid = tid >> 6;

    __shared__ float sw[NP1];
    __shared__ float rbuf[8];
    __shared__ float cbuf[512];

    // sentinel alpha
    float s = 0.f;
    for (int a = tid; a < 512; a += 256)
        s += tanhf(satt[(size_t)b * 512 + a] + hatt[(size_t)b * 512 + a]) * Wal[a];
    #pragma unroll
    for (int off = 32; off >= 1; off >>= 1) s += __shfl_down(s, off);
    if (lane == 0) rbuf[wid] = s;
    __syncthreads();
    if (tid == 0) sw[196] = rbuf[0] + rbuf[1] + rbuf[2] + rbuf[3];
    if (tid < 196) sw[tid] = alph[(size_t)b * 196 + tid];
    __syncthreads();

    // softmax over 197
    const float v = (tid < NP1) ? sw[tid] : -INFINITY;
    float m = v;
    #pragma unroll
    for (int off = 32; off >= 1; off >>= 1) m = fmaxf(m, __shfl_down(m, off));
    if (lane == 0) rbuf[wid] = m;
    __syncthreads();
    m = fmaxf(fmaxf(rbuf[0], rbuf[1]), fmaxf(rbuf[2], rbuf[3]));
    const float e = (tid < NP1) ? expf(v - m) : 0.f;
    float lsum = e;
    #pragma unroll
    for (int off = 32; off >= 1; off >>= 1) lsum += __shfl_down(lsum, off);
    if (lane == 0) rbuf[4 + wid] = lsum;
    __syncthreads();
    lsum = rbuf[4] + rbuf[5] + rbuf[6] + rbuf[7];
    const float wgt = e / lsum;
    if (tid < NP1) { wout[(size_t)b * NP1 + tid] = wgt; sw[tid] = wgt; }
    if (tid == 196) beta[b] = wgt;
    __syncthreads();

    // context[b,:] = sum_p w[p]*spatial[b,p,:] + w[196]*sa[b,:]
    const int hq = (tid & 127) << 2;
    const int ph = tid >> 7;
    float4 c = make_float4(0.f, 0.f, 0.f, 0.f);
    const float* sp = spatial + (size_t)b * 196 * 512 + hq;
    const int p0 = ph * 98;
    #pragma unroll 2
    for (int p = p0; p < p0 + 98; ++p) {
        const float wp = sw[p];
        const float4 sv = *(const float4*)(sp + (size_t)p * 512);
        c.x += wp * sv.x; c.y += wp * sv.y; c.z += wp * sv.z; c.w += wp * sv.w;
    }
    if (ph) *(float4*)(cbuf + hq) = c;
    __syncthreads();
    if (!ph) {
        const float wp = sw[196];
        const float4 sv = *(const float4*)(sa + (size_t)b * 512 + hq);
        const float4 o = *(const float4*)(cbuf + hq);
        c.x += wp * sv.x + o.x; c.y += wp * sv.y + o.y;
        c.z += wp * sv.z + o.z; c.w += wp * sv.w + o.w;
        *(float4*)(context + (size_t)b * 512 + hq) = c;
    }
}

// ---------------------------------------------------------------------------
extern "C" void kernel_launch(void* const* d_in, const int* in_sizes, int n_in,
                              void* d_out, int out_size, void* d_ws, size_t ws_size,
                              hipStream_t stream)
{
    const float* spatial = (const float*)d_in[0];
    const float* dec     = (const float*)d_in[1];
    const float* st      = (const float*)d_in[2];
    const float* W_sa    = (const float*)d_in[3];
    const float* b_sa    = (const float*)d_in[4];
    const float* W_satt  = (const float*)d_in[5];
    const float* b_satt  = (const float*)d_in[6];
    const float* W_ha    = (const float*)d_in[7];
    const float* b_ha    = (const float*)d_in[8];
    const float* W_hatt  = (const float*)d_in[9];
    const float* b_hatt  = (const float*)d_in[10];
    const float* W_va    = (const float*)d_in[11];
    const float* b_va    = (const float*)d_in[12];
    const float* W_al    = (const float*)d_in[13];
    // d_in[14] = b_al: constant across p -> softmax invariant, unused.
    const float* W_ch    = (const float*)d_in[15];
    const float* b_ch    = (const float*)d_in[16];

    float* out  = (float*)d_out;                 // B x 512
    float* wout = out + (size_t)BN * HN;         // B x 197
    float* beta = wout + (size_t)BN * NP1;       // B

    float* ws   = (float*)d_ws;
    float* sa   = ws;                            // B x 512
    float* ha   = sa + (size_t)BN * HN;          // B x 512
    float* satt = ha + (size_t)BN * HN;          // B x 512
    float* hatt = satt + (size_t)BN * HN;        // B x 512
    float* alph = hatt + (size_t)BN * HN;        // B x 196
    float* ctx  = alph + (size_t)BN * PN;        // B x 512
    // Bpack (bf16 512x512 = 512 KB) aliases ctx: dead before ctx is written.
    unsigned short* Bpack = (unsigned short*)ctx;

    const dim3 blk(256);

    wpack_kernel<<<dim3(32, 16), blk, 0, stream>>>(W_va, Bpack);

    // relu(st@W_sa+b_sa) -> sa  ||  tanh(dec@W_ha+b_ha) -> ha
    gemm32_pair_kernel<1, 2><<<dim3(8, 64), blk, 0, stream>>>(
        st, W_sa, b_sa, sa, dec, W_ha, b_ha, ha);
    // sa@W_satt+b_satt -> satt  ||  ha@W_hatt+b_hatt -> hatt
    gemm32_pair_kernel<0, 0><<<dim3(8, 64), blk, 0, stream>>>(
        sa, W_satt, b_satt, satt, ha, W_hatt, b_hatt, hatt);

    alpha_mfma3_kernel<<<dim3(6272), blk, 0, stream>>>(spatial, Bpack, b_va, hatt, W_al, alph);

    softmax_context_kernel<<<dim3(BN), blk, 0, stream>>>(alph, satt, hatt, W_al, spatial,
                                                         sa, wout, beta, ctx);

    gemm32_fin_kernel<<<dim3(8, 32), blk, 0, stream>>>(ctx, ha, W_ch, b_ch, out);
}